// Round 1
// baseline (278.130 us; speedup 1.0000x reference)
//
#include <hip/hip_runtime.h>
#include <hip/hip_bf16.h>

// out[0, t, e] = cos(t) * sum_q W[e,q] + b[e]
// T = 65536, EMBED = 1024, output fp32, 256 MiB -> store-BW bound.

#define EMBED 1024
#define ROWS_PER_BLOCK 16

__global__ __launch_bounds__(256)
void pe_quantum_kernel(const float* __restrict__ W,
                       const float* __restrict__ b,
                       float* __restrict__ out,
                       int T) {
    // 256 threads x 4 floats = 1024 = EMBED
    const int e0 = threadIdx.x * 4;

    // Per-thread reduction of W rows (8 floats each) for its 4 embed slots.
    // 36 KB total across W+b -> L1/L2 resident; HBM cost negligible.
    float4 sv;
    {
        const float4* Wv = (const float4*)W;   // W[e*8 + ...] -> Wv[e*2], Wv[e*2+1]
        float s[4];
        #pragma unroll
        for (int i = 0; i < 4; ++i) {
            const int e = e0 + i;
            float4 a = Wv[e * 2 + 0];
            float4 c = Wv[e * 2 + 1];
            s[i] = ((a.x + a.y) + (a.z + a.w)) + ((c.x + c.y) + (c.z + c.w));
        }
        sv.x = s[0]; sv.y = s[1]; sv.z = s[2]; sv.w = s[3];
    }
    const float4 bb = *(const float4*)(b + e0);

    const int t0 = blockIdx.x * ROWS_PER_BLOCK;
    #pragma unroll
    for (int r = 0; r < ROWS_PER_BLOCK; ++r) {
        const int t = t0 + r;
        if (t >= T) break;
        const float c = cosf((float)t);   // wave-uniform value; precise enough (t < 2^16)
        float4 o;
        o.x = fmaf(c, sv.x, bb.x);
        o.y = fmaf(c, sv.y, bb.y);
        o.z = fmaf(c, sv.z, bb.z);
        o.w = fmaf(c, sv.w, bb.w);
        *(float4*)(out + (size_t)t * EMBED + e0) = o;   // coalesced 16B/lane stores
    }
}

extern "C" void kernel_launch(void* const* d_in, const int* in_sizes, int n_in,
                              void* d_out, int out_size, void* d_ws, size_t ws_size,
                              hipStream_t stream) {
    // setup_inputs order: x (unused), W [1024,8], b [1024]
    const float* W = (const float*)d_in[1];
    const float* b = (const float*)d_in[2];
    float* out = (float*)d_out;

    const int T = out_size / EMBED;  // 65536
    const int grid = (T + ROWS_PER_BLOCK - 1) / ROWS_PER_BLOCK;  // 4096 blocks
    pe_quantum_kernel<<<grid, 256, 0, stream>>>(W, b, out, T);
}

// Round 3
// 270.131 us; speedup vs baseline: 1.0296x; 1.0296x over previous
//
#include <hip/hip_runtime.h>
#include <hip/hip_bf16.h>

// out[0, t, e] = cos(t) * sum_q W[e,q] + b[e]
// T = 65536, EMBED = 1024, output fp32 = 256 MiB -> pure store-BW bound.
// Roofline: 268 MB / ~5.9 TB/s (demonstrated fill rate) ~= 45 us.

#define EMBED 1024
#define ROWS_PER_BLOCK 32

typedef float v4f __attribute__((ext_vector_type(4)));  // native vec for nontemporal builtin

__global__ __launch_bounds__(256)
void pe_quantum_kernel(const float* __restrict__ W,
                       const float* __restrict__ b,
                       float* __restrict__ out,
                       int T) {
    // 256 threads x 4 floats = 1024 = EMBED; each thread owns a fixed float4 e-slice.
    const int e0 = threadIdx.x * 4;

    // Per-thread row-sums of W for its 4 embed slots (W is 32 KB, L2-resident).
    float s0, s1, s2, s3;
    {
        const float4* Wv = (const float4*)W;   // W row e -> Wv[e*2], Wv[e*2+1]
        float s[4];
        #pragma unroll
        for (int i = 0; i < 4; ++i) {
            const int e = e0 + i;
            float4 a = Wv[e * 2 + 0];
            float4 c = Wv[e * 2 + 1];
            s[i] = ((a.x + a.y) + (a.z + a.w)) + ((c.x + c.y) + (c.z + c.w));
        }
        s0 = s[0]; s1 = s[1]; s2 = s[2]; s3 = s[3];
    }
    const float4 bb = *(const float4*)(b + e0);

    const int t0 = blockIdx.x * ROWS_PER_BLOCK;

    // cos(t0+r) via Chebyshev recurrence: c_{n+1} = 2cos(1)*c_n - c_{n-1}.
    // 2 cosf calls instead of 32; fp32 drift over 32 steps ~1e-5, threshold 4.5e-2.
    float c_prev = cosf((float)t0);
    float c_cur  = cosf((float)(t0 + 1));
    const float K = 1.0806046117362795f;  // 2*cos(1)

    float* p = out + (size_t)t0 * EMBED + e0;

    #pragma unroll
    for (int r = 0; r < ROWS_PER_BLOCK; ++r) {
        const float c = c_prev;
        v4f o;
        o.x = fmaf(c, s0, bb.x);
        o.y = fmaf(c, s1, bb.y);
        o.z = fmaf(c, s2, bb.z);
        o.w = fmaf(c, s3, bb.w);
        __builtin_nontemporal_store(o, (v4f*)p);  // streaming store, skip L2 alloc
        p += EMBED;
        // advance recurrence
        const float c_next = fmaf(K, c_cur, -c_prev);
        c_prev = c_cur;
        c_cur  = c_next;
    }
}

extern "C" void kernel_launch(void* const* d_in, const int* in_sizes, int n_in,
                              void* d_out, int out_size, void* d_ws, size_t ws_size,
                              hipStream_t stream) {
    // setup_inputs order: x (unused), W [1024,8], b [1024]
    const float* W = (const float*)d_in[1];
    const float* b = (const float*)d_in[2];
    float* out = (float*)d_out;

    const int T = out_size / EMBED;  // 65536
    const int grid = (T + ROWS_PER_BLOCK - 1) / ROWS_PER_BLOCK;  // 2048 blocks
    pe_quantum_kernel<<<grid, 256, 0, stream>>>(W, b, out, T);
}